// Round 8
// baseline (9027.289 us; speedup 1.0000x reference)
//
#include <hip/hip_runtime.h>
#include <hip/hip_bf16.h>
#include <math.h>

// ---- problem constants ----
#define DURZ 6
#define DURX 5
#define SEQ 257
#define LZ 1542   // 6*257 zr tokens
#define LX 1285   // 5*257 xa tokens
#define LT 2827   // LZ+LX
#define DM 512
#define NHEADS 8
#define DH 64
#define HIDDEN 2048

// ---------------- sentinel fill (diagnostic readout channel) ----------------
__global__ void fill_kernel(float* __restrict__ out, int n, float v) {
    int i = blockIdx.x * blockDim.x + threadIdx.x;
    if (i < n) out[i] = v;
}

// ---------------- embed: build initial state (LT x 512 fp32) ----------------
__global__ void embed_kernel(const float* __restrict__ z,
                             const float* __restrict__ frames,
                             const int* __restrict__ actions,
                             const float* __restrict__ W_patch,
                             const float* __restrict__ b_patch,
                             const float* __restrict__ registers,
                             const float* __restrict__ pe,
                             const float* __restrict__ action_emb,
                             float* __restrict__ state) {
    int T = blockIdx.x;
    int tid = threadIdx.x;
    bool is_z = T < LZ;
    int T2 = is_z ? T : T - LZ;
    int f = T2 / SEQ, t = T2 % SEQ;
    if (t < 256) {
        const float* src = is_z ? z : frames;
        int hp = t >> 4, wp = t & 15;
        float pv[12];
#pragma unroll
        for (int c = 0; c < 3; c++)
#pragma unroll
            for (int ph = 0; ph < 2; ph++)
#pragma unroll
                for (int pw = 0; pw < 2; pw++)
                    pv[c * 4 + ph * 2 + pw] =
                        src[((f * 3 + c) * 32 + (hp * 2 + ph)) * 32 + (wp * 2 + pw)];
        for (int d = tid; d < DM; d += 256) {
            float acc = b_patch[d];
#pragma unroll
            for (int j = 0; j < 12; j++) acc += pv[j] * W_patch[j * DM + d];
            acc += pe[t * DM + d];
            state[T * DM + d] = acc;
        }
    } else if (is_z) {
        for (int d = tid; d < DM; d += 256) state[T * DM + d] = registers[d];
    } else {
        int a = actions[f];
        for (int d = tid; d < DM; d += 256) state[T * DM + d] = action_emb[a * DM + d];
    }
}

// ---------------- cond vectors: raw + silu, rows 0..5 = ts frames, 6 = clean --
__global__ void cond_kernel(const int* __restrict__ ts,
                            const float* __restrict__ time_emb,
                            float* __restrict__ condraw,
                            float* __restrict__ condsilu) {
    int idx = blockIdx.x * blockDim.x + threadIdx.x;
    if (idx >= 7 * 512) return;
    int r = idx >> 9;
    int j = idx & 511;
    int tsr = (r < 6) ? ts[r] : 0;
    float x = time_emb[tsr * 512 + j];
    condraw[idx] = x;
    condsilu[idx] = x / (1.0f + expf(-x));
}

// ---------------- params[i][r][c] ----------------
// c: [0,1024) mod1 (scale|shift), [1024,2048) mod2 (scale|shift),
//    [2048,2560) g1, [2560,3072) g2
__global__ void params_kernel(const float* __restrict__ condraw,
                              const float* __restrict__ condsilu,
                              const float* __restrict__ W_mod1,
                              const float* __restrict__ b_mod1,
                              const float* __restrict__ W_mod2,
                              const float* __restrict__ b_mod2,
                              const float* __restrict__ W_g1,
                              const float* __restrict__ b_g1,
                              const float* __restrict__ W_g2,
                              const float* __restrict__ b_g2,
                              float* __restrict__ params) {
    int idx = blockIdx.x * blockDim.x + threadIdx.x;
    if (idx >= 6 * 7 * 3072) return;
    int i = idx / 21504;
    int rem = idx % 21504;
    int r = rem / 3072;
    int c = rem % 3072;
    const float* cv;
    const float* W;
    float bias;
    int ldw;
    if (c < 1024) {
        cv = condsilu + r * 512;
        W = W_mod1 + (size_t)i * 512 * 1024 + c; ldw = 1024;
        bias = b_mod1[i * 1024 + c];
    } else if (c < 2048) {
        int cc = c - 1024;
        cv = condsilu + r * 512;
        W = W_mod2 + (size_t)i * 512 * 1024 + cc; ldw = 1024;
        bias = b_mod2[i * 1024 + cc];
    } else if (c < 2560) {
        int cc = c - 2048;
        cv = condraw + r * 512;
        W = W_g1 + (size_t)i * 512 * 512 + cc; ldw = 512;
        bias = b_g1[i * 512 + cc];
    } else {
        int cc = c - 2560;
        cv = condraw + r * 512;
        W = W_g2 + (size_t)i * 512 * 512 + cc; ldw = 512;
        bias = b_g2[i * 512 + cc];
    }
    float acc = bias;
    for (int j = 0; j < 512; j++) acc += cv[j] * W[(size_t)j * ldw];
    params[idx] = acc;
}

// ---------------- LN + AdaLN modulate: y = LN(x)*(1+scale)+shift ------------
__global__ __launch_bounds__(256) void lnmod_kernel(const float* __restrict__ x,
                                                    float* __restrict__ y,
                                                    const float* __restrict__ params,
                                                    int mod_off) {
    int T = blockIdx.x;
    int tid = threadIdx.x;
    int r = (T < LZ) ? (T / SEQ) : 6;
    const float* prow = params + r * 3072 + mod_off;
    const float* xr = x + (size_t)T * DM;
    float v0 = xr[tid], v1 = xr[tid + 256];
    float s_ = v0 + v1, q_ = v0 * v0 + v1 * v1;
#pragma unroll
    for (int off = 32; off; off >>= 1) {
        s_ += __shfl_down(s_, off);
        q_ += __shfl_down(q_, off);
    }
    __shared__ float sh[8];
    int wave = tid >> 6, lane = tid & 63;
    if (lane == 0) { sh[wave] = s_; sh[4 + wave] = q_; }
    __syncthreads();
    float sum = sh[0] + sh[1] + sh[2] + sh[3];
    float sq = sh[4] + sh[5] + sh[6] + sh[7];
    float mu = sum * (1.0f / 512.0f);
    float var = sq * (1.0f / 512.0f) - mu * mu;
    float rstd = rsqrtf(var + 1e-5f);
    int d0 = tid, d1 = tid + 256;
    y[(size_t)T * DM + d0] = (v0 - mu) * rstd * (1.0f + prow[d0]) + prow[512 + d0];
    y[(size_t)T * DM + d1] = (v1 - mu) * rstd * (1.0f + prow[d1]) + prow[512 + d1];
}

// ---------------- GEMM: C[M,N] = A[M,K] @ W[K,N] + bias (all f32) -----------
__global__ __launch_bounds__(256) void gemm_bias(const float* __restrict__ A,
                                                 const float* __restrict__ W,
                                                 const float* __restrict__ bias,
                                                 float* __restrict__ C,
                                                 int M, int N, int K) {
    __shared__ __align__(16) float As[16][68];
    __shared__ __align__(16) float Bs[16][68];
    int tid = threadIdx.x;
    int tx = tid & 15, ty = tid >> 4;
    int m0 = blockIdx.y * 64, n0 = blockIdx.x * 64;
    float acc[4][4] = {{0.0f}};
    int am = tid >> 2, ak = (tid & 3) * 4;
    int bk = tid >> 6, bn = tid & 63;
    bool avalid = (m0 + am) < M;
    for (int k0 = 0; k0 < K; k0 += 16) {
        float4 av = make_float4(0.f, 0.f, 0.f, 0.f);
        if (avalid) av = *(const float4*)(A + (size_t)(m0 + am) * K + k0 + ak);
        float bv[4];
#pragma unroll
        for (int j = 0; j < 4; ++j)
            bv[j] = W[(size_t)(k0 + bk + 4 * j) * N + n0 + bn];
        __syncthreads();
        As[ak + 0][am] = av.x; As[ak + 1][am] = av.y;
        As[ak + 2][am] = av.z; As[ak + 3][am] = av.w;
#pragma unroll
        for (int j = 0; j < 4; ++j) Bs[bk + 4 * j][bn] = bv[j];
        __syncthreads();
#pragma unroll
        for (int kk = 0; kk < 16; ++kk) {
            float4 a4 = *(const float4*)(&As[kk][ty * 4]);
            float4 b4 = *(const float4*)(&Bs[kk][tx * 4]);
            const float aa[4] = {a4.x, a4.y, a4.z, a4.w};
            const float bb[4] = {b4.x, b4.y, b4.z, b4.w};
#pragma unroll
            for (int i = 0; i < 4; ++i)
#pragma unroll
                for (int j = 0; j < 4; ++j) acc[i][j] += aa[i] * bb[j];
        }
    }
#pragma unroll
    for (int i = 0; i < 4; ++i) {
        int m = m0 + ty * 4 + i;
        if (m < M) {
#pragma unroll
            for (int j = 0; j < 4; ++j) {
                int n = n0 + tx * 4 + j;
                C[(size_t)m * N + n] = acc[i][j] + bias[n];
            }
        }
    }
}

// ---- GEMM accumulate: C (+)= A @ W  (+ bias if first), all f32 -------------
__global__ __launch_bounds__(256) void gemm_acc(const float* __restrict__ A,
                                                const float* __restrict__ W,
                                                const float* __restrict__ bias,
                                                float* __restrict__ C,
                                                int M, int N, int K, int first) {
    __shared__ __align__(16) float As[16][68];
    __shared__ __align__(16) float Bs[16][68];
    int tid = threadIdx.x;
    int tx = tid & 15, ty = tid >> 4;
    int m0 = blockIdx.y * 64, n0 = blockIdx.x * 64;
    float acc[4][4] = {{0.0f}};
    int am = tid >> 2, ak = (tid & 3) * 4;
    int bk = tid >> 6, bn = tid & 63;
    bool avalid = (m0 + am) < M;
    for (int k0 = 0; k0 < K; k0 += 16) {
        float4 av = make_float4(0.f, 0.f, 0.f, 0.f);
        if (avalid) av = *(const float4*)(A + (size_t)(m0 + am) * K + k0 + ak);
        float bv[4];
#pragma unroll
        for (int j = 0; j < 4; ++j)
            bv[j] = W[(size_t)(k0 + bk + 4 * j) * N + n0 + bn];
        __syncthreads();
        As[ak + 0][am] = av.x; As[ak + 1][am] = av.y;
        As[ak + 2][am] = av.z; As[ak + 3][am] = av.w;
#pragma unroll
        for (int j = 0; j < 4; ++j) Bs[bk + 4 * j][bn] = bv[j];
        __syncthreads();
#pragma unroll
        for (int kk = 0; kk < 16; ++kk) {
            float4 a4 = *(const float4*)(&As[kk][ty * 4]);
            float4 b4 = *(const float4*)(&Bs[kk][tx * 4]);
            const float aa[4] = {a4.x, a4.y, a4.z, a4.w};
            const float bb[4] = {b4.x, b4.y, b4.z, b4.w};
#pragma unroll
            for (int i = 0; i < 4; ++i)
#pragma unroll
                for (int j = 0; j < 4; ++j) acc[i][j] += aa[i] * bb[j];
        }
    }
#pragma unroll
    for (int i = 0; i < 4; ++i) {
        int m = m0 + ty * 4 + i;
        if (m < M) {
#pragma unroll
            for (int j = 0; j < 4; ++j) {
                int n = n0 + tx * 4 + j;
                size_t idx = (size_t)m * N + n;
                float prev = first ? bias[n] : C[idx];
                C[idx] = prev + acc[i][j];
            }
        }
    }
}

// ---- GEGLU chunk: H[M,512] = (A@Wa+ba)*gelu(A@Wg+bg) for col chunk ---------
__global__ __launch_bounds__(256) void gemm_geglu_chunk(const float* __restrict__ A,
                                                        const float* __restrict__ W,
                                                        const float* __restrict__ bias,
                                                        float* __restrict__ H,
                                                        int M, int chunk) {
    __shared__ __align__(16) float As[16][68];
    __shared__ __align__(16) float Ba[16][68];
    __shared__ __align__(16) float Bg[16][68];
    int tid = threadIdx.x;
    int tx = tid & 15, ty = tid >> 4;
    int m0 = blockIdx.y * 64, n0 = blockIdx.x * 64;
    int ca0 = chunk * 512;
    float acca[4][4] = {{0.0f}}, accg[4][4] = {{0.0f}};
    int am = tid >> 2, ak = (tid & 3) * 4;
    int bk = tid >> 6, bn = tid & 63;
    bool avalid = (m0 + am) < M;
    for (int k0 = 0; k0 < 512; k0 += 16) {
        float4 av = make_float4(0.f, 0.f, 0.f, 0.f);
        if (avalid) av = *(const float4*)(A + (size_t)(m0 + am) * DM + k0 + ak);
        float bva[4], bvg[4];
#pragma unroll
        for (int j = 0; j < 4; ++j) {
            size_t rowoff = (size_t)(k0 + bk + 4 * j) * 4096 + ca0 + n0 + bn;
            bva[j] = W[rowoff];
            bvg[j] = W[rowoff + 2048];
        }
        __syncthreads();
        As[ak + 0][am] = av.x; As[ak + 1][am] = av.y;
        As[ak + 2][am] = av.z; As[ak + 3][am] = av.w;
#pragma unroll
        for (int j = 0; j < 4; ++j) { Ba[bk + 4 * j][bn] = bva[j]; Bg[bk + 4 * j][bn] = bvg[j]; }
        __syncthreads();
#pragma unroll
        for (int kk = 0; kk < 16; ++kk) {
            float4 a4 = *(const float4*)(&As[kk][ty * 4]);
            float4 ba4 = *(const float4*)(&Ba[kk][tx * 4]);
            float4 bg4 = *(const float4*)(&Bg[kk][tx * 4]);
            const float aa[4] = {a4.x, a4.y, a4.z, a4.w};
            const float bb[4] = {ba4.x, ba4.y, ba4.z, ba4.w};
            const float gg[4] = {bg4.x, bg4.y, bg4.z, bg4.w};
#pragma unroll
            for (int i = 0; i < 4; ++i)
#pragma unroll
                for (int j = 0; j < 4; ++j) {
                    acca[i][j] += aa[i] * bb[j];
                    accg[i][j] += aa[i] * gg[j];
                }
        }
    }
#pragma unroll
    for (int i = 0; i < 4; ++i) {
        int m = m0 + ty * 4 + i;
        if (m < M) {
#pragma unroll
            for (int j = 0; j < 4; ++j) {
                int n = n0 + tx * 4 + j;
                float a = acca[i][j] + bias[ca0 + n];
                float g = accg[i][j] + bias[2048 + ca0 + n];
                float gel = 0.5f * g * (1.0f + erff(g * 0.70710678118654752f));
                H[(size_t)m * 512 + n] = a * gel;
            }
        }
    }
}

// ---------------- attention (f32, two contiguous key ranges) ----------------
static __device__ __forceinline__ float dot64(const float* __restrict__ qs,
                                              const float* __restrict__ kp) {
    float a0 = 0, a1 = 0, a2 = 0, a3 = 0;
#pragma unroll
    for (int d = 0; d < 64; d += 4) {
        a0 += qs[d] * kp[d];
        a1 += qs[d + 1] * kp[d + 1];
        a2 += qs[d + 2] * kp[d + 2];
        a3 += qs[d + 3] * kp[d + 3];
    }
    return (a0 + a1) + (a2 + a3);
}

__global__ __launch_bounds__(64) void attn_kernel(const float* __restrict__ Q,
                                                  const float* __restrict__ Kb,
                                                  const float* __restrict__ Vb,
                                                  float* __restrict__ O,
                                                  int self_mode) {
    int qt = blockIdx.x;
    int h = blockIdx.y;
    int lane = threadIdx.x;
    __shared__ float qs[64];
    __shared__ float sc[1288];
    int qrow, base0, len0, base1, len1;
    if (!self_mode) {
        qrow = qt;
        int f = qt / SEQ;
        base0 = f * SEQ; len0 = SEQ;
        int jl = f - 4; if (jl < 0) jl = 0;
        base1 = LZ + jl * SEQ; len1 = (f - jl) * SEQ;
    } else {
        int f = qt / SEQ;
        qrow = LZ + qt;
        base0 = LZ; len0 = (f + 1) * SEQ;
        base1 = 0; len1 = 0;
    }
    int hoff = h * DH;
    qs[lane] = Q[(size_t)qrow * DM + hoff + lane];
    __syncthreads();
    for (int o = lane; o < len0; o += 64)
        sc[o] = dot64(qs, Kb + (size_t)(base0 + o) * DM + hoff) * 0.125f;
    for (int o = lane; o < len1; o += 64)
        sc[len0 + o] = dot64(qs, Kb + (size_t)(base1 + o) * DM + hoff) * 0.125f;
    __syncthreads();
    int nk = len0 + len1;
    float m = -1e30f;
    for (int o = lane; o < nk; o += 64) m = fmaxf(m, sc[o]);
#pragma unroll
    for (int off = 32; off; off >>= 1) m = fmaxf(m, __shfl_xor(m, off));
    float sum = 0.0f;
    __syncthreads();
    for (int o = lane; o < nk; o += 64) {
        float p = __expf(sc[o] - m);
        sc[o] = p;
        sum += p;
    }
#pragma unroll
    for (int off = 32; off; off >>= 1) sum += __shfl_xor(sum, off);
    __syncthreads();
    float inv = 1.0f / sum;
    float acc = 0.0f, acc2 = 0.0f;
    {
        const float* vp = Vb + (size_t)base0 * DM + hoff + lane;
        int o = 0;
        for (; o + 2 <= len0; o += 2) {
            acc += sc[o] * vp[(size_t)o * DM];
            acc2 += sc[o + 1] * vp[(size_t)(o + 1) * DM];
        }
        if (o < len0) acc += sc[o] * vp[(size_t)o * DM];
    }
    if (len1) {
        const float* vp = Vb + (size_t)base1 * DM + hoff + lane;
        int o = 0;
        for (; o + 2 <= len1; o += 2) {
            acc += sc[len0 + o] * vp[(size_t)o * DM];
            acc2 += sc[len0 + o + 1] * vp[(size_t)(o + 1) * DM];
        }
        if (o < len1) acc += sc[len0 + o] * vp[(size_t)o * DM];
    }
    O[(size_t)qrow * DM + hoff + lane] = (acc + acc2) * inv;
}

// ---------------- gate1 + residual add: y2 = xn*g1 + proj -------------------
__global__ void gate1add_kernel(const float* __restrict__ xn,
                                const float* __restrict__ proj,
                                float* __restrict__ y2,
                                const float* __restrict__ params) {
    int idx = blockIdx.x * blockDim.x + threadIdx.x;
    if (idx >= LT * DM) return;
    int T = idx >> 9, d = idx & 511;
    int r = (T < LZ) ? (T / SEQ) : 6;
    y2[idx] = xn[idx] * params[r * 3072 + 2048 + d] + proj[idx];
}

// ---------------- gate2: state = proj * g2 ----------------
__global__ void gate2_kernel(const float* __restrict__ src, float* __restrict__ state,
                             const float* __restrict__ params) {
    int idx = blockIdx.x * blockDim.x + threadIdx.x;
    if (idx >= LT * DM) return;
    int T = idx >> 9, d = idx & 511;
    int r = (T < LZ) ? (T / SEQ) : 6;
    state[idx] = src[idx] * params[r * 3072 + 2560 + d];
}

// ---------------- unpatch to FP32 output (the round-8 fix) ------------------
__global__ void unpatch_kernel(const float* __restrict__ state,
                               const float* __restrict__ Wu,
                               const float* __restrict__ bu,
                               float* __restrict__ out) {
    int idx = blockIdx.x * blockDim.x + threadIdx.x;
    if (idx >= DURZ * 3 * 32 * 32) return;
    int w = idx & 31, hh = (idx >> 5) & 31, c = (idx >> 10) % 3, f = idx / (3 * 1024);
    int t = (hh >> 1) * 16 + (w >> 1);
    int j = c * 4 + (hh & 1) * 2 + (w & 1);
    const float* xr = state + (size_t)(f * SEQ + t) * DM;
    float acc = bu[j];
    for (int k = 0; k < DM; ++k) acc += xr[k] * Wu[k * 12 + j];
    out[idx] = acc;   // f32 — reference output dtype is float32
}

extern "C" void kernel_launch(void* const* d_in, const int* in_sizes, int n_in,
                              void* d_out, int out_size, void* d_ws, size_t ws_size,
                              hipStream_t stream) {
    // ---- host-side interface verification (index-coded sentinel readout) ----
    static const int expected_sizes[32] = {
        18432, 15360, 6, 6,                    // z, frames, actions, ts
        6144, 512, 6144, 12,                   // W_patch, b_patch, W_unpatch, b_unpatch
        512, 131072, 1536, 512000,             // registers, pe_grid, action_emb, time_emb
        3145728, 6144, 3145728, 6144,          // W_mod1, b_mod1, W_mod2, b_mod2
        1572864, 3072, 1572864, 3072,          // W_q, b_q, W_k, b_k
        1572864, 3072, 1572864, 3072,          // W_v, b_v, W_o, b_o
        1572864, 3072, 1572864, 3072,          // W_g1, b_g1, W_g2, b_g2
        12582912, 24576, 6291456, 3072         // W_geglu, b_geglu, W_ffout, b_ffout
    };
    if (n_in != 32) {
        fill_kernel<<<(18432 + 255) / 256, 256, 0, stream>>>((float*)d_out, 18432, 3.0f);
        return;
    }
    for (int i = 0; i < 32; ++i) {
        if (in_sizes[i] != expected_sizes[i]) {
            fill_kernel<<<(18432 + 255) / 256, 256, 0, stream>>>((float*)d_out, 18432,
                                                                 4.0f + (float)i);
            return;
        }
    }

    const float* z = (const float*)d_in[0];
    const float* frames = (const float*)d_in[1];
    const int* actions = (const int*)d_in[2];
    const int* ts = (const int*)d_in[3];
    const float* W_patch = (const float*)d_in[4];
    const float* b_patch = (const float*)d_in[5];
    const float* W_unpatch = (const float*)d_in[6];
    const float* b_unpatch = (const float*)d_in[7];
    const float* registers = (const float*)d_in[8];
    const float* pe_grid = (const float*)d_in[9];
    const float* action_emb = (const float*)d_in[10];
    const float* time_emb = (const float*)d_in[11];
    const float* W_mod1 = (const float*)d_in[12];
    const float* b_mod1 = (const float*)d_in[13];
    const float* W_mod2 = (const float*)d_in[14];
    const float* b_mod2 = (const float*)d_in[15];
    const float* W_q = (const float*)d_in[16];
    const float* b_q = (const float*)d_in[17];
    const float* W_k = (const float*)d_in[18];
    const float* b_k = (const float*)d_in[19];
    const float* W_v = (const float*)d_in[20];
    const float* b_v = (const float*)d_in[21];
    const float* W_o = (const float*)d_in[22];
    const float* b_o = (const float*)d_in[23];
    const float* W_g1 = (const float*)d_in[24];
    const float* b_g1 = (const float*)d_in[25];
    const float* W_g2 = (const float*)d_in[26];
    const float* b_g2 = (const float*)d_in[27];
    const float* W_geglu = (const float*)d_in[28];
    const float* b_geglu = (const float*)d_in[29];
    const float* W_ffout = (const float*)d_in[30];
    const float* b_ffout = (const float*)d_in[31];

    // ---- plain f32 workspace, ~46.9 MiB (fits: round-5 sentinel didn't fire)
    const size_t S = (size_t)LT * DM;  // 1,447,424
    size_t need = (8 * S + 129024 + 7168) * sizeof(float);
    if (ws_size < need) {
        fill_kernel<<<(18432 + 255) / 256, 256, 0, stream>>>((float*)d_out, 18432, 40.0f);
        return;
    }
    float* ws = (float*)d_ws;
    float* state = ws;
    float* xn = ws + S;
    float* qb = ws + 2 * S;
    float* kb = ws + 3 * S;
    float* vb = ws + 4 * S;
    float* attno = ws + 5 * S;   // reused as y2 after o-proj
    float* proj = ws + 6 * S;
    float* hc = ws + 7 * S;
    float* params = ws + 8 * S;
    float* condraw = params + 129024;
    float* condsilu = condraw + 3584;

    embed_kernel<<<LT, 256, 0, stream>>>(z, frames, actions, W_patch, b_patch,
                                         registers, pe_grid, action_emb, state);
    cond_kernel<<<(7 * 512 + 255) / 256, 256, 0, stream>>>(ts, time_emb, condraw, condsilu);
    params_kernel<<<(6 * 7 * 3072 + 255) / 256, 256, 0, stream>>>(
        condraw, condsilu, W_mod1, b_mod1, W_mod2, b_mod2, W_g1, b_g1, W_g2, b_g2, params);

    dim3 g512(8, (LT + 63) / 64);
    int ew = (LT * DM + 255) / 256;
    for (int i = 0; i < 6; ++i) {
        const float* P = params + i * 21504;
        lnmod_kernel<<<LT, 256, 0, stream>>>(state, xn, P, 0);
        gemm_bias<<<g512, 256, 0, stream>>>(xn, W_q + (size_t)i * DM * DM, b_q + i * DM,
                                            qb, LT, DM, DM);
        gemm_bias<<<g512, 256, 0, stream>>>(xn, W_k + (size_t)i * DM * DM, b_k + i * DM,
                                            kb, LT, DM, DM);
        gemm_bias<<<g512, 256, 0, stream>>>(xn, W_v + (size_t)i * DM * DM, b_v + i * DM,
                                            vb, LT, DM, DM);
        attn_kernel<<<dim3(LZ, NHEADS), 64, 0, stream>>>(qb, kb, vb, attno, 0);
        attn_kernel<<<dim3(LX, NHEADS), 64, 0, stream>>>(qb, kb, vb, attno, 1);
        gemm_bias<<<g512, 256, 0, stream>>>(attno, W_o + (size_t)i * DM * DM, b_o + i * DM,
                                            proj, LT, DM, DM);
        gate1add_kernel<<<ew, 256, 0, stream>>>(xn, proj, attno, P);  // attno := y2
        lnmod_kernel<<<LT, 256, 0, stream>>>(attno, xn, P, 1024);
        for (int c = 0; c < 4; ++c) {
            gemm_geglu_chunk<<<g512, 256, 0, stream>>>(
                xn, W_geglu + (size_t)i * DM * 4096, b_geglu + i * 4096, hc, LT, c);
            gemm_acc<<<g512, 256, 0, stream>>>(
                hc, W_ffout + (size_t)i * HIDDEN * DM + (size_t)c * 512 * DM,
                b_ffout + i * DM, proj, LT, DM, 512, c == 0);
        }
        gate2_kernel<<<ew, 256, 0, stream>>>(proj, state, P);
    }
    unpatch_kernel<<<(DURZ * 3 * 32 * 32 + 255) / 256, 256, 0, stream>>>(
        state, W_unpatch, b_unpatch, (float*)d_out);
}

// Round 9
// 4902.153 us; speedup vs baseline: 1.8415x; 1.8415x over previous
//
#include <hip/hip_runtime.h>
#include <hip/hip_bf16.h>
#include <math.h>

// ---- problem constants ----
#define DURZ 6
#define DURX 5
#define SEQ 257
#define LZ 1542   // 6*257 zr tokens
#define LX 1285   // 5*257 xa tokens
#define LT 2827   // LZ+LX
#define DM 512
#define NHEADS 8
#define DH 64
#define HIDDEN 2048

// ---------------- sentinel fill (diagnostic readout channel) ----------------
__global__ void fill_kernel(float* __restrict__ out, int n, float v) {
    int i = blockIdx.x * blockDim.x + threadIdx.x;
    if (i < n) out[i] = v;
}

// ---------------- embed: build initial state (LT x 512 fp32) ----------------
__global__ void embed_kernel(const float* __restrict__ z,
                             const float* __restrict__ frames,
                             const int* __restrict__ actions,
                             const float* __restrict__ W_patch,
                             const float* __restrict__ b_patch,
                             const float* __restrict__ registers,
                             const float* __restrict__ pe,
                             const float* __restrict__ action_emb,
                             float* __restrict__ state) {
    int T = blockIdx.x;
    int tid = threadIdx.x;
    bool is_z = T < LZ;
    int T2 = is_z ? T : T - LZ;
    int f = T2 / SEQ, t = T2 % SEQ;
    if (t < 256) {
        const float* src = is_z ? z : frames;
        int hp = t >> 4, wp = t & 15;
        float pv[12];
#pragma unroll
        for (int c = 0; c < 3; c++)
#pragma unroll
            for (int ph = 0; ph < 2; ph++)
#pragma unroll
                for (int pw = 0; pw < 2; pw++)
                    pv[c * 4 + ph * 2 + pw] =
                        src[((f * 3 + c) * 32 + (hp * 2 + ph)) * 32 + (wp * 2 + pw)];
        for (int d = tid; d < DM; d += 256) {
            float acc = b_patch[d];
#pragma unroll
            for (int j = 0; j < 12; j++) acc += pv[j] * W_patch[j * DM + d];
            acc += pe[t * DM + d];
            state[T * DM + d] = acc;
        }
    } else if (is_z) {
        for (int d = tid; d < DM; d += 256) state[T * DM + d] = registers[d];
    } else {
        int a = actions[f];
        for (int d = tid; d < DM; d += 256) state[T * DM + d] = action_emb[a * DM + d];
    }
}

// ---------------- cond vectors: raw + silu, rows 0..5 = ts frames, 6 = clean --
__global__ void cond_kernel(const int* __restrict__ ts,
                            const float* __restrict__ time_emb,
                            float* __restrict__ condraw,
                            float* __restrict__ condsilu) {
    int idx = blockIdx.x * blockDim.x + threadIdx.x;
    if (idx >= 7 * 512) return;
    int r = idx >> 9;
    int j = idx & 511;
    int tsr = (r < 6) ? ts[r] : 0;
    float x = time_emb[tsr * 512 + j];
    condraw[idx] = x;
    condsilu[idx] = x / (1.0f + expf(-x));
}

// ---------------- params[i][r][c] ----------------
// c: [0,1024) mod1 (scale|shift), [1024,2048) mod2 (scale|shift),
//    [2048,2560) g1, [2560,3072) g2
__global__ void params_kernel(const float* __restrict__ condraw,
                              const float* __restrict__ condsilu,
                              const float* __restrict__ W_mod1,
                              const float* __restrict__ b_mod1,
                              const float* __restrict__ W_mod2,
                              const float* __restrict__ b_mod2,
                              const float* __restrict__ W_g1,
                              const float* __restrict__ b_g1,
                              const float* __restrict__ W_g2,
                              const float* __restrict__ b_g2,
                              float* __restrict__ params) {
    int idx = blockIdx.x * blockDim.x + threadIdx.x;
    if (idx >= 6 * 7 * 3072) return;
    int i = idx / 21504;
    int rem = idx % 21504;
    int r = rem / 3072;
    int c = rem % 3072;
    const float* cv;
    const float* W;
    float bias;
    int ldw;
    if (c < 1024) {
        cv = condsilu + r * 512;
        W = W_mod1 + (size_t)i * 512 * 1024 + c; ldw = 1024;
        bias = b_mod1[i * 1024 + c];
    } else if (c < 2048) {
        int cc = c - 1024;
        cv = condsilu + r * 512;
        W = W_mod2 + (size_t)i * 512 * 1024 + cc; ldw = 1024;
        bias = b_mod2[i * 1024 + cc];
    } else if (c < 2560) {
        int cc = c - 2048;
        cv = condraw + r * 512;
        W = W_g1 + (size_t)i * 512 * 512 + cc; ldw = 512;
        bias = b_g1[i * 512 + cc];
    } else {
        int cc = c - 2560;
        cv = condraw + r * 512;
        W = W_g2 + (size_t)i * 512 * 512 + cc; ldw = 512;
        bias = b_g2[i * 512 + cc];
    }
    float acc = bias;
    for (int j = 0; j < 512; j++) acc += cv[j] * W[(size_t)j * ldw];
    params[idx] = acc;
}

// ---------------- LN + AdaLN modulate: y = LN(x)*(1+scale)+shift ------------
__global__ __launch_bounds__(256) void lnmod_kernel(const float* __restrict__ x,
                                                    float* __restrict__ y,
                                                    const float* __restrict__ params,
                                                    int mod_off) {
    int T = blockIdx.x;
    int tid = threadIdx.x;
    int r = (T < LZ) ? (T / SEQ) : 6;
    const float* prow = params + r * 3072 + mod_off;
    const float* xr = x + (size_t)T * DM;
    float v0 = xr[tid], v1 = xr[tid + 256];
    float s_ = v0 + v1, q_ = v0 * v0 + v1 * v1;
#pragma unroll
    for (int off = 32; off; off >>= 1) {
        s_ += __shfl_down(s_, off);
        q_ += __shfl_down(q_, off);
    }
    __shared__ float sh[8];
    int wave = tid >> 6, lane = tid & 63;
    if (lane == 0) { sh[wave] = s_; sh[4 + wave] = q_; }
    __syncthreads();
    float sum = sh[0] + sh[1] + sh[2] + sh[3];
    float sq = sh[4] + sh[5] + sh[6] + sh[7];
    float mu = sum * (1.0f / 512.0f);
    float var = sq * (1.0f / 512.0f) - mu * mu;
    float rstd = rsqrtf(var + 1e-5f);
    int d0 = tid, d1 = tid + 256;
    y[(size_t)T * DM + d0] = (v0 - mu) * rstd * (1.0f + prow[d0]) + prow[512 + d0];
    y[(size_t)T * DM + d1] = (v1 - mu) * rstd * (1.0f + prow[d1]) + prow[512 + d1];
}

// ---------------- GEMM: C[M,N] = A[M,K] @ W[K,N] + bias (all f32) -----------
__global__ __launch_bounds__(256) void gemm_bias(const float* __restrict__ A,
                                                 const float* __restrict__ W,
                                                 const float* __restrict__ bias,
                                                 float* __restrict__ C,
                                                 int M, int N, int K) {
    __shared__ __align__(16) float As[16][68];
    __shared__ __align__(16) float Bs[16][68];
    int tid = threadIdx.x;
    int tx = tid & 15, ty = tid >> 4;
    int m0 = blockIdx.y * 64, n0 = blockIdx.x * 64;
    float acc[4][4] = {{0.0f}};
    int am = tid >> 2, ak = (tid & 3) * 4;
    int bk = tid >> 6, bn = tid & 63;
    bool avalid = (m0 + am) < M;
    for (int k0 = 0; k0 < K; k0 += 16) {
        float4 av = make_float4(0.f, 0.f, 0.f, 0.f);
        if (avalid) av = *(const float4*)(A + (size_t)(m0 + am) * K + k0 + ak);
        float bv[4];
#pragma unroll
        for (int j = 0; j < 4; ++j)
            bv[j] = W[(size_t)(k0 + bk + 4 * j) * N + n0 + bn];
        __syncthreads();
        As[ak + 0][am] = av.x; As[ak + 1][am] = av.y;
        As[ak + 2][am] = av.z; As[ak + 3][am] = av.w;
#pragma unroll
        for (int j = 0; j < 4; ++j) Bs[bk + 4 * j][bn] = bv[j];
        __syncthreads();
#pragma unroll
        for (int kk = 0; kk < 16; ++kk) {
            float4 a4 = *(const float4*)(&As[kk][ty * 4]);
            float4 b4 = *(const float4*)(&Bs[kk][tx * 4]);
            const float aa[4] = {a4.x, a4.y, a4.z, a4.w};
            const float bb[4] = {b4.x, b4.y, b4.z, b4.w};
#pragma unroll
            for (int i = 0; i < 4; ++i)
#pragma unroll
                for (int j = 0; j < 4; ++j) acc[i][j] += aa[i] * bb[j];
        }
    }
#pragma unroll
    for (int i = 0; i < 4; ++i) {
        int m = m0 + ty * 4 + i;
        if (m < M) {
#pragma unroll
            for (int j = 0; j < 4; ++j) {
                int n = n0 + tx * 4 + j;
                C[(size_t)m * N + n] = acc[i][j] + bias[n];
            }
        }
    }
}

// ---- GEMM accumulate: C (+)= A @ W  (+ bias if first), all f32 -------------
__global__ __launch_bounds__(256) void gemm_acc(const float* __restrict__ A,
                                                const float* __restrict__ W,
                                                const float* __restrict__ bias,
                                                float* __restrict__ C,
                                                int M, int N, int K, int first) {
    __shared__ __align__(16) float As[16][68];
    __shared__ __align__(16) float Bs[16][68];
    int tid = threadIdx.x;
    int tx = tid & 15, ty = tid >> 4;
    int m0 = blockIdx.y * 64, n0 = blockIdx.x * 64;
    float acc[4][4] = {{0.0f}};
    int am = tid >> 2, ak = (tid & 3) * 4;
    int bk = tid >> 6, bn = tid & 63;
    bool avalid = (m0 + am) < M;
    for (int k0 = 0; k0 < K; k0 += 16) {
        float4 av = make_float4(0.f, 0.f, 0.f, 0.f);
        if (avalid) av = *(const float4*)(A + (size_t)(m0 + am) * K + k0 + ak);
        float bv[4];
#pragma unroll
        for (int j = 0; j < 4; ++j)
            bv[j] = W[(size_t)(k0 + bk + 4 * j) * N + n0 + bn];
        __syncthreads();
        As[ak + 0][am] = av.x; As[ak + 1][am] = av.y;
        As[ak + 2][am] = av.z; As[ak + 3][am] = av.w;
#pragma unroll
        for (int j = 0; j < 4; ++j) Bs[bk + 4 * j][bn] = bv[j];
        __syncthreads();
#pragma unroll
        for (int kk = 0; kk < 16; ++kk) {
            float4 a4 = *(const float4*)(&As[kk][ty * 4]);
            float4 b4 = *(const float4*)(&Bs[kk][tx * 4]);
            const float aa[4] = {a4.x, a4.y, a4.z, a4.w};
            const float bb[4] = {b4.x, b4.y, b4.z, b4.w};
#pragma unroll
            for (int i = 0; i < 4; ++i)
#pragma unroll
                for (int j = 0; j < 4; ++j) acc[i][j] += aa[i] * bb[j];
        }
    }
#pragma unroll
    for (int i = 0; i < 4; ++i) {
        int m = m0 + ty * 4 + i;
        if (m < M) {
#pragma unroll
            for (int j = 0; j < 4; ++j) {
                int n = n0 + tx * 4 + j;
                size_t idx = (size_t)m * N + n;
                float prev = first ? bias[n] : C[idx];
                C[idx] = prev + acc[i][j];
            }
        }
    }
}

// ---- GEGLU chunk: H[M,512] = (A@Wa+ba)*gelu(A@Wg+bg) for col chunk ---------
__global__ __launch_bounds__(256) void gemm_geglu_chunk(const float* __restrict__ A,
                                                        const float* __restrict__ W,
                                                        const float* __restrict__ bias,
                                                        float* __restrict__ H,
                                                        int M, int chunk) {
    __shared__ __align__(16) float As[16][68];
    __shared__ __align__(16) float Ba[16][68];
    __shared__ __align__(16) float Bg[16][68];
    int tid = threadIdx.x;
    int tx = tid & 15, ty = tid >> 4;
    int m0 = blockIdx.y * 64, n0 = blockIdx.x * 64;
    int ca0 = chunk * 512;
    float acca[4][4] = {{0.0f}}, accg[4][4] = {{0.0f}};
    int am = tid >> 2, ak = (tid & 3) * 4;
    int bk = tid >> 6, bn = tid & 63;
    bool avalid = (m0 + am) < M;
    for (int k0 = 0; k0 < 512; k0 += 16) {
        float4 av = make_float4(0.f, 0.f, 0.f, 0.f);
        if (avalid) av = *(const float4*)(A + (size_t)(m0 + am) * DM + k0 + ak);
        float bva[4], bvg[4];
#pragma unroll
        for (int j = 0; j < 4; ++j) {
            size_t rowoff = (size_t)(k0 + bk + 4 * j) * 4096 + ca0 + n0 + bn;
            bva[j] = W[rowoff];
            bvg[j] = W[rowoff + 2048];
        }
        __syncthreads();
        As[ak + 0][am] = av.x; As[ak + 1][am] = av.y;
        As[ak + 2][am] = av.z; As[ak + 3][am] = av.w;
#pragma unroll
        for (int j = 0; j < 4; ++j) { Ba[bk + 4 * j][bn] = bva[j]; Bg[bk + 4 * j][bn] = bvg[j]; }
        __syncthreads();
#pragma unroll
        for (int kk = 0; kk < 16; ++kk) {
            float4 a4 = *(const float4*)(&As[kk][ty * 4]);
            float4 ba4 = *(const float4*)(&Ba[kk][tx * 4]);
            float4 bg4 = *(const float4*)(&Bg[kk][tx * 4]);
            const float aa[4] = {a4.x, a4.y, a4.z, a4.w};
            const float bb[4] = {ba4.x, ba4.y, ba4.z, ba4.w};
            const float gg[4] = {bg4.x, bg4.y, bg4.z, bg4.w};
#pragma unroll
            for (int i = 0; i < 4; ++i)
#pragma unroll
                for (int j = 0; j < 4; ++j) {
                    acca[i][j] += aa[i] * bb[j];
                    accg[i][j] += aa[i] * gg[j];
                }
        }
    }
#pragma unroll
    for (int i = 0; i < 4; ++i) {
        int m = m0 + ty * 4 + i;
        if (m < M) {
#pragma unroll
            for (int j = 0; j < 4; ++j) {
                int n = n0 + tx * 4 + j;
                float a = acca[i][j] + bias[ca0 + n];
                float g = accg[i][j] + bias[2048 + ca0 + n];
                float gel = 0.5f * g * (1.0f + erff(g * 0.70710678118654752f));
                H[(size_t)m * 512 + n] = a * gel;
            }
        }
    }
}

// ---- flash attention: block = (64-query tile, frame, head), exact softmax ---
// blockIdx.y < 6: cross (zr queries); else self (xa queries, frame y-6).
__global__ __launch_bounds__(256) void fattn_kernel(const float* __restrict__ Q,
                                                    const float* __restrict__ K,
                                                    const float* __restrict__ V,
                                                    float* __restrict__ O) {
    __shared__ __align__(16) float Qs[64][68];   // [d][m]
    __shared__ __align__(16) float KPs[64][68];  // K tile [d][n], then P tile [n][m]
    __shared__ __align__(16) float Vs[64][68];   // [n][dv]
    int tid = threadIdx.x;
    int tx = tid & 15, ty = tid >> 4;
    int h = blockIdx.z;
    int hoff = h * DH;

    int qbase, base0, len0, base1, len1;
    if (blockIdx.y < 6) {
        int f = blockIdx.y;
        qbase = f * SEQ;
        base0 = f * SEQ; len0 = SEQ;
        int jl = f - 4; if (jl < 0) jl = 0;
        base1 = LZ + jl * SEQ; len1 = (f - jl) * SEQ;
    } else {
        int f = blockIdx.y - 6;
        qbase = LZ + f * SEQ;
        base0 = LZ; len0 = (f + 1) * SEQ;
        base1 = 0; len1 = 0;
    }
    int q0 = blockIdx.x * 64;                  // 0,64,128,192,256
    int qvalid = SEQ - q0; if (qvalid > 64) qvalid = 64;

    {   // stage Q tile -> Qs[d][m]
        int am = tid >> 2, ad = (tid & 3) * 4;
        const float* qp = Q + (size_t)(qbase + q0 + am) * DM + hoff;
        bool v = am < qvalid;
#pragma unroll
        for (int c = 0; c < 4; ++c) {
            float4 q4 = v ? *(const float4*)(qp + ad + c * 16) : make_float4(0, 0, 0, 0);
            Qs[ad + c * 16 + 0][am] = q4.x;
            Qs[ad + c * 16 + 1][am] = q4.y;
            Qs[ad + c * 16 + 2][am] = q4.z;
            Qs[ad + c * 16 + 3][am] = q4.w;
        }
    }
    float o_acc[4][4] = {{0.0f}};
    float m_i[4] = {-1e30f, -1e30f, -1e30f, -1e30f};
    float l_i[4] = {0.0f, 0.0f, 0.0f, 0.0f};

    for (int rng = 0; rng < 2; ++rng) {
        int base = rng ? base1 : base0;
        int len = rng ? len1 : len0;
        for (int t0 = 0; t0 < len; t0 += 64) {
            int valid = len - t0; if (valid > 64) valid = 64;
            __syncthreads();  // prev tile's PV done; (first iter: after Q stage)
            {   // stage K -> KPs[d][n]
                int an = tid >> 2, ad = (tid & 3) * 4;
                const float* kp = K + (size_t)(base + t0 + an) * DM + hoff;
                bool v = an < valid;
#pragma unroll
                for (int c = 0; c < 4; ++c) {
                    float4 k4 = v ? *(const float4*)(kp + ad + c * 16) : make_float4(0, 0, 0, 0);
                    KPs[ad + c * 16 + 0][an] = k4.x;
                    KPs[ad + c * 16 + 1][an] = k4.y;
                    KPs[ad + c * 16 + 2][an] = k4.z;
                    KPs[ad + c * 16 + 3][an] = k4.w;
                }
                // stage V -> Vs[n][dv] (float4 both sides)
#pragma unroll
                for (int c = 0; c < 4; ++c) {
                    int flat = c * 256 + tid;
                    int n = flat >> 4, dg = (flat & 15) * 4;
                    float4 v4 = (n < valid)
                        ? *(const float4*)(V + (size_t)(base + t0 + n) * DM + hoff + dg)
                        : make_float4(0, 0, 0, 0);
                    *(float4*)(&Vs[n][dg]) = v4;
                }
            }
            __syncthreads();
            // S = (Q K^T) * 0.125
            float p[4][4] = {{0.0f}};
            for (int d = 0; d < 64; ++d) {
                float4 a4 = *(const float4*)(&Qs[d][ty * 4]);
                float4 b4 = *(const float4*)(&KPs[d][tx * 4]);
                const float aa[4] = {a4.x, a4.y, a4.z, a4.w};
                const float bb[4] = {b4.x, b4.y, b4.z, b4.w};
#pragma unroll
                for (int i = 0; i < 4; ++i)
#pragma unroll
                    for (int j = 0; j < 4; ++j) p[i][j] += aa[i] * bb[j];
            }
            // online softmax update (exact)
            float alpha[4];
#pragma unroll
            for (int i = 0; i < 4; ++i) {
#pragma unroll
                for (int j = 0; j < 4; ++j)
                    p[i][j] = (tx * 4 + j < valid) ? p[i][j] * 0.125f : -1e30f;
                float rmax = fmaxf(fmaxf(p[i][0], p[i][1]), fmaxf(p[i][2], p[i][3]));
#pragma unroll
                for (int msk = 1; msk < 16; msk <<= 1)
                    rmax = fmaxf(rmax, __shfl_xor(rmax, msk));
                float mnew = fmaxf(m_i[i], rmax);
                alpha[i] = __expf(m_i[i] - mnew);
                float rsum = 0.0f;
#pragma unroll
                for (int j = 0; j < 4; ++j) {
                    p[i][j] = __expf(p[i][j] - mnew);
                    rsum += p[i][j];
                }
#pragma unroll
                for (int msk = 1; msk < 16; msk <<= 1)
                    rsum += __shfl_xor(rsum, msk);
                l_i[i] = l_i[i] * alpha[i] + rsum;
                m_i[i] = mnew;
#pragma unroll
                for (int j = 0; j < 4; ++j) o_acc[i][j] *= alpha[i];
            }
            __syncthreads();  // all S reads of KPs done
            // write P -> KPs[n][m]
#pragma unroll
            for (int i = 0; i < 4; ++i)
#pragma unroll
                for (int j = 0; j < 4; ++j)
                    KPs[tx * 4 + j][ty * 4 + i] = p[i][j];
            __syncthreads();
            // O += P @ V
            for (int n = 0; n < 64; ++n) {
                float4 p4 = *(const float4*)(&KPs[n][ty * 4]);
                float4 v4 = *(const float4*)(&Vs[n][tx * 4]);
                const float pp[4] = {p4.x, p4.y, p4.z, p4.w};
                const float vv[4] = {v4.x, v4.y, v4.z, v4.w};
#pragma unroll
                for (int i = 0; i < 4; ++i)
#pragma unroll
                    for (int j = 0; j < 4; ++j) o_acc[i][j] += pp[i] * vv[j];
            }
        }
    }
#pragma unroll
    for (int i = 0; i < 4; ++i) {
        int row = ty * 4 + i;
        if (row < qvalid) {
            float inv = 1.0f / l_i[i];
            float4 o4 = make_float4(o_acc[i][0] * inv, o_acc[i][1] * inv,
                                    o_acc[i][2] * inv, o_acc[i][3] * inv);
            *(float4*)(O + (size_t)(qbase + q0 + row) * DM + hoff + tx * 4) = o4;
        }
    }
}

// ---------------- gate1 + residual add: y2 = xn*g1 + proj -------------------
__global__ void gate1add_kernel(const float* __restrict__ xn,
                                const float* __restrict__ proj,
                                float* __restrict__ y2,
                                const float* __restrict__ params) {
    int idx = blockIdx.x * blockDim.x + threadIdx.x;
    if (idx >= LT * DM) return;
    int T = idx >> 9, d = idx & 511;
    int r = (T < LZ) ? (T / SEQ) : 6;
    y2[idx] = xn[idx] * params[r * 3072 + 2048 + d] + proj[idx];
}

// ---------------- gate2: state = proj * g2 ----------------
__global__ void gate2_kernel(const float* __restrict__ src, float* __restrict__ state,
                             const float* __restrict__ params) {
    int idx = blockIdx.x * blockDim.x + threadIdx.x;
    if (idx >= LT * DM) return;
    int T = idx >> 9, d = idx & 511;
    int r = (T < LZ) ? (T / SEQ) : 6;
    state[idx] = src[idx] * params[r * 3072 + 2560 + d];
}

// ---------------- unpatch to FP32 output ------------------
__global__ void unpatch_kernel(const float* __restrict__ state,
                               const float* __restrict__ Wu,
                               const float* __restrict__ bu,
                               float* __restrict__ out) {
    int idx = blockIdx.x * blockDim.x + threadIdx.x;
    if (idx >= DURZ * 3 * 32 * 32) return;
    int w = idx & 31, hh = (idx >> 5) & 31, c = (idx >> 10) % 3, f = idx / (3 * 1024);
    int t = (hh >> 1) * 16 + (w >> 1);
    int j = c * 4 + (hh & 1) * 2 + (w & 1);
    const float* xr = state + (size_t)(f * SEQ + t) * DM;
    float acc = bu[j];
    for (int k = 0; k < DM; ++k) acc += xr[k] * Wu[k * 12 + j];
    out[idx] = acc;
}

extern "C" void kernel_launch(void* const* d_in, const int* in_sizes, int n_in,
                              void* d_out, int out_size, void* d_ws, size_t ws_size,
                              hipStream_t stream) {
    static const int expected_sizes[32] = {
        18432, 15360, 6, 6,
        6144, 512, 6144, 12,
        512, 131072, 1536, 512000,
        3145728, 6144, 3145728, 6144,
        1572864, 3072, 1572864, 3072,
        1572864, 3072, 1572864, 3072,
        1572864, 3072, 1572864, 3072,
        12582912, 24576, 6291456, 3072
    };
    if (n_in != 32) {
        fill_kernel<<<(18432 + 255) / 256, 256, 0, stream>>>((float*)d_out, 18432, 3.0f);
        return;
    }
    for (int i = 0; i < 32; ++i) {
        if (in_sizes[i] != expected_sizes[i]) {
            fill_kernel<<<(18432 + 255) / 256, 256, 0, stream>>>((float*)d_out, 18432,
                                                                 4.0f + (float)i);
            return;
        }
    }

    const float* z = (const float*)d_in[0];
    const float* frames = (const float*)d_in[1];
    const int* actions = (const int*)d_in[2];
    const int* ts = (const int*)d_in[3];
    const float* W_patch = (const float*)d_in[4];
    const float* b_patch = (const float*)d_in[5];
    const float* W_unpatch = (const float*)d_in[6];
    const float* b_unpatch = (const float*)d_in[7];
    const float* registers = (const float*)d_in[8];
    const float* pe_grid = (const float*)d_in[9];
    const float* action_emb = (const float*)d_in[10];
    const float* time_emb = (const float*)d_in[11];
    const float* W_mod1 = (const float*)d_in[12];
    const float* b_mod1 = (const float*)d_in[13];
    const float* W_mod2 = (const float*)d_in[14];
    const float* b_mod2 = (const float*)d_in[15];
    const float* W_q = (const float*)d_in[16];
    const float* b_q = (const float*)d_in[17];
    const float* W_k = (const float*)d_in[18];
    const float* b_k = (const float*)d_in[19];
    const float* W_v = (const float*)d_in[20];
    const float* b_v = (const float*)d_in[21];
    const float* W_o = (const float*)d_in[22];
    const float* b_o = (const float*)d_in[23];
    const float* W_g1 = (const float*)d_in[24];
    const float* b_g1 = (const float*)d_in[25];
    const float* W_g2 = (const float*)d_in[26];
    const float* b_g2 = (const float*)d_in[27];
    const float* W_geglu = (const float*)d_in[28];
    const float* b_geglu = (const float*)d_in[29];
    const float* W_ffout = (const float*)d_in[30];
    const float* b_ffout = (const float*)d_in[31];

    const size_t S = (size_t)LT * DM;  // 1,447,424
    size_t need = (8 * S + 129024 + 7168) * sizeof(float);
    if (ws_size < need) {
        fill_kernel<<<(18432 + 255) / 256, 256, 0, stream>>>((float*)d_out, 18432, 40.0f);
        return;
    }
    float* ws = (float*)d_ws;
    float* state = ws;
    float* xn = ws + S;
    float* qb = ws + 2 * S;
    float* kb = ws + 3 * S;
    float* vb = ws + 4 * S;
    float* attno = ws + 5 * S;   // reused as y2 after o-proj
    float* proj = ws + 6 * S;
    float* hc = ws + 7 * S;
    float* params = ws + 8 * S;
    float* condraw = params + 129024;
    float* condsilu = condraw + 3584;

    embed_kernel<<<LT, 256, 0, stream>>>(z, frames, actions, W_patch, b_patch,
                                         registers, pe_grid, action_emb, state);
    cond_kernel<<<(7 * 512 + 255) / 256, 256, 0, stream>>>(ts, time_emb, condraw, condsilu);
    params_kernel<<<(6 * 7 * 3072 + 255) / 256, 256, 0, stream>>>(
        condraw, condsilu, W_mod1, b_mod1, W_mod2, b_mod2, W_g1, b_g1, W_g2, b_g2, params);

    dim3 g512(8, (LT + 63) / 64);
    dim3 gattn(5, 11, NHEADS);   // 5 q-tiles x (6 cross + 5 self frames) x heads
    int ew = (LT * DM + 255) / 256;
    for (int i = 0; i < 6; ++i) {
        const float* P = params + i * 21504;
        lnmod_kernel<<<LT, 256, 0, stream>>>(state, xn, P, 0);
        gemm_bias<<<g512, 256, 0, stream>>>(xn, W_q + (size_t)i * DM * DM, b_q + i * DM,
                                            qb, LT, DM, DM);
        gemm_bias<<<g512, 256, 0, stream>>>(xn, W_k + (size_t)i * DM * DM, b_k + i * DM,
                                            kb, LT, DM, DM);
        gemm_bias<<<g512, 256, 0, stream>>>(xn, W_v + (size_t)i * DM * DM, b_v + i * DM,
                                            vb, LT, DM, DM);
        fattn_kernel<<<gattn, 256, 0, stream>>>(qb, kb, vb, attno);
        gemm_bias<<<g512, 256, 0, stream>>>(attno, W_o + (size_t)i * DM * DM, b_o + i * DM,
                                            proj, LT, DM, DM);
        gate1add_kernel<<<ew, 256, 0, stream>>>(xn, proj, attno, P);  // attno := y2
        lnmod_kernel<<<LT, 256, 0, stream>>>(attno, xn, P, 1024);
        for (int c = 0; c < 4; ++c) {
            gemm_geglu_chunk<<<g512, 256, 0, stream>>>(
                xn, W_geglu + (size_t)i * DM * 4096, b_geglu + i * 4096, hc, LT, c);
            gemm_acc<<<g512, 256, 0, stream>>>(
                hc, W_ffout + (size_t)i * HIDDEN * DM + (size_t)c * 512 * DM,
                b_ffout + i * DM, proj, LT, DM, 512, c == 0);
        }
        gate2_kernel<<<ew, 256, 0, stream>>>(proj, state, P);
    }
    unpatch_kernel<<<(DURZ * 3 * 32 * 32 + 255) / 256, 256, 0, stream>>>(
        state, W_unpatch, b_unpatch, (float*)d_out);
}

// Round 11
// 3251.290 us; speedup vs baseline: 2.7765x; 1.5078x over previous
//
#include <hip/hip_runtime.h>
#include <hip/hip_bf16.h>
#include <math.h>

// ---- problem constants ----
#define DURZ 6
#define DURX 5
#define SEQ 257
#define LZ 1542   // 6*257 zr tokens
#define LX 1285   // 5*257 xa tokens
#define LT 2827   // LZ+LX
#define DM 512
#define NHEADS 8
#define DH 64
#define HIDDEN 2048

typedef __bf16 bf16x8 __attribute__((ext_vector_type(8)));
typedef float f32x4 __attribute__((ext_vector_type(4)));

// ---------------- sentinel fill (diagnostic readout channel) ----------------
__global__ void fill_kernel(float* __restrict__ out, int n, float v) {
    int i = blockIdx.x * blockDim.x + threadIdx.x;
    if (i < n) out[i] = v;
}

// ---------------- embed ----------------
__global__ void embed_kernel(const float* __restrict__ z,
                             const float* __restrict__ frames,
                             const int* __restrict__ actions,
                             const float* __restrict__ W_patch,
                             const float* __restrict__ b_patch,
                             const float* __restrict__ registers,
                             const float* __restrict__ pe,
                             const float* __restrict__ action_emb,
                             float* __restrict__ state) {
    int T = blockIdx.x;
    int tid = threadIdx.x;
    bool is_z = T < LZ;
    int T2 = is_z ? T : T - LZ;
    int f = T2 / SEQ, t = T2 % SEQ;
    if (t < 256) {
        const float* src = is_z ? z : frames;
        int hp = t >> 4, wp = t & 15;
        float pv[12];
#pragma unroll
        for (int c = 0; c < 3; c++)
#pragma unroll
            for (int ph = 0; ph < 2; ph++)
#pragma unroll
                for (int pw = 0; pw < 2; pw++)
                    pv[c * 4 + ph * 2 + pw] =
                        src[((f * 3 + c) * 32 + (hp * 2 + ph)) * 32 + (wp * 2 + pw)];
        for (int d = tid; d < DM; d += 256) {
            float acc = b_patch[d];
#pragma unroll
            for (int j = 0; j < 12; j++) acc += pv[j] * W_patch[j * DM + d];
            acc += pe[t * DM + d];
            state[T * DM + d] = acc;
        }
    } else if (is_z) {
        for (int d = tid; d < DM; d += 256) state[T * DM + d] = registers[d];
    } else {
        int a = actions[f];
        for (int d = tid; d < DM; d += 256) state[T * DM + d] = action_emb[a * DM + d];
    }
}

// ---------------- cond vectors ----------------
__global__ void cond_kernel(const int* __restrict__ ts,
                            const float* __restrict__ time_emb,
                            float* __restrict__ condraw,
                            float* __restrict__ condsilu) {
    int idx = blockIdx.x * blockDim.x + threadIdx.x;
    if (idx >= 7 * 512) return;
    int r = idx >> 9;
    int j = idx & 511;
    int tsr = (r < 6) ? ts[r] : 0;
    float x = time_emb[tsr * 512 + j];
    condraw[idx] = x;
    condsilu[idx] = x / (1.0f + expf(-x));
}

// ---------------- params[i][r][c] ----------------
__global__ void params_kernel(const float* __restrict__ condraw,
                              const float* __restrict__ condsilu,
                              const float* __restrict__ W_mod1,
                              const float* __restrict__ b_mod1,
                              const float* __restrict__ W_mod2,
                              const float* __restrict__ b_mod2,
                              const float* __restrict__ W_g1,
                              const float* __restrict__ b_g1,
                              const float* __restrict__ W_g2,
                              const float* __restrict__ b_g2,
                              float* __restrict__ params) {
    int idx = blockIdx.x * blockDim.x + threadIdx.x;
    if (idx >= 6 * 7 * 3072) return;
    int i = idx / 21504;
    int rem = idx % 21504;
    int r = rem / 3072;
    int c = rem % 3072;
    const float* cv;
    const float* W;
    float bias;
    int ldw;
    if (c < 1024) {
        cv = condsilu + r * 512;
        W = W_mod1 + (size_t)i * 512 * 1024 + c; ldw = 1024;
        bias = b_mod1[i * 1024 + c];
    } else if (c < 2048) {
        int cc = c - 1024;
        cv = condsilu + r * 512;
        W = W_mod2 + (size_t)i * 512 * 1024 + cc; ldw = 1024;
        bias = b_mod2[i * 1024 + cc];
    } else if (c < 2560) {
        int cc = c - 2048;
        cv = condraw + r * 512;
        W = W_g1 + (size_t)i * 512 * 512 + cc; ldw = 512;
        bias = b_g1[i * 512 + cc];
    } else {
        int cc = c - 2560;
        cv = condraw + r * 512;
        W = W_g2 + (size_t)i * 512 * 512 + cc; ldw = 512;
        bias = b_g2[i * 512 + cc];
    }
    float acc = bias;
    for (int j = 0; j < 512; j++) acc += cv[j] * W[(size_t)j * ldw];
    params[idx] = acc;
}

// ---------------- LN + AdaLN modulate ------------
__global__ __launch_bounds__(256) void lnmod_kernel(const float* __restrict__ x,
                                                    float* __restrict__ y,
                                                    const float* __restrict__ params,
                                                    int mod_off) {
    int T = blockIdx.x;
    int tid = threadIdx.x;
    int r = (T < LZ) ? (T / SEQ) : 6;
    const float* prow = params + r * 3072 + mod_off;
    const float* xr = x + (size_t)T * DM;
    float v0 = xr[tid], v1 = xr[tid + 256];
    float s_ = v0 + v1, q_ = v0 * v0 + v1 * v1;
#pragma unroll
    for (int off = 32; off; off >>= 1) {
        s_ += __shfl_down(s_, off);
        q_ += __shfl_down(q_, off);
    }
    __shared__ float sh[8];
    int wave = tid >> 6, lane = tid & 63;
    if (lane == 0) { sh[wave] = s_; sh[4 + wave] = q_; }
    __syncthreads();
    float sum = sh[0] + sh[1] + sh[2] + sh[3];
    float sq = sh[4] + sh[5] + sh[6] + sh[7];
    float mu = sum * (1.0f / 512.0f);
    float var = sq * (1.0f / 512.0f) - mu * mu;
    float rstd = rsqrtf(var + 1e-5f);
    int d0 = tid, d1 = tid + 256;
    y[(size_t)T * DM + d0] = (v0 - mu) * rstd * (1.0f + prow[d0]) + prow[512 + d0];
    y[(size_t)T * DM + d1] = (v1 - mu) * rstd * (1.0f + prow[d1]) + prow[512 + d1];
}

// ================= split-precision bf16 MFMA GEMM family =====================
// f32 operands split hi/lo: x = hi + lo, hi=(bf16)x, lo=(bf16)(x-hi).
// A@W ~= Ah@Wh + Ah@Wl + Al@Wh  (3 MFMAs, error ~2^-17 relative).
// 128x128 tile, 4 waves, each 4x4 of 16x16x32. C/D (m89): row=(lane>>4)*4+reg,
// col=lane&15. LDS rows padded to 40 bf16 (80B).

#define SPLIT_STORE(TH, TL, smv, khv, cc, val)              \
    {                                                       \
        float _v = (val);                                   \
        __bf16 _h = (__bf16)_v;                             \
        TH[smv][khv + cc] = _h;                             \
        TL[smv][khv + cc] = (__bf16)(_v - (float)_h);       \
    }

#define MFMA3(accv, ah, al, bh, bl)                                            \
    accv = __builtin_amdgcn_mfma_f32_16x16x32_bf16(al, bh, accv, 0, 0, 0);     \
    accv = __builtin_amdgcn_mfma_f32_16x16x32_bf16(ah, bl, accv, 0, 0, 0);     \
    accv = __builtin_amdgcn_mfma_f32_16x16x32_bf16(ah, bh, accv, 0, 0, 0);

// ---- fused q/k/v projection ------------------------------------------------
__global__ __launch_bounds__(256) void mgemm_qkv(const float* __restrict__ A,
                                                 const float* __restrict__ Wq,
                                                 const float* __restrict__ Wk,
                                                 const float* __restrict__ Wv,
                                                 const float* __restrict__ bq,
                                                 const float* __restrict__ bk,
                                                 const float* __restrict__ bv,
                                                 float* __restrict__ Cq,
                                                 float* __restrict__ Ck,
                                                 float* __restrict__ Cv, int M) {
    __shared__ __align__(16) __bf16 Ah[128][40], Al[128][40];
    __shared__ __align__(16) __bf16 Bh[128][40], Bl[128][40];
    const int K = 512, N = 512;
    int tid = threadIdx.x;
    int sel = blockIdx.x >> 2;
    int n0 = (blockIdx.x & 3) * 128;
    int m0 = blockIdx.y * 128;
    const float* W = sel == 0 ? Wq : (sel == 1 ? Wk : Wv);
    const float* bias = sel == 0 ? bq : (sel == 1 ? bk : bv);
    float* C = sel == 0 ? Cq : (sel == 1 ? Ck : Cv);
    int w = tid >> 6, lane = tid & 63;
    int wm = (w >> 1) * 64, wn = (w & 1) * 64;
    int q = lane >> 4, lr = lane & 15;
    int sm = tid & 127, kh = (tid >> 7) * 16;
    bool mval = (m0 + sm) < M;
    f32x4 acc[4][4];
#pragma unroll
    for (int i = 0; i < 4; ++i)
#pragma unroll
        for (int j = 0; j < 4; ++j)
#pragma unroll
            for (int r = 0; r < 4; ++r) acc[i][j][r] = 0.0f;
    for (int k0 = 0; k0 < K; k0 += 32) {
        float av[16], wv[16];
        const float* ap = A + (size_t)(m0 + sm) * K + k0 + kh;
#pragma unroll
        for (int c = 0; c < 4; ++c) {
            float4 t = mval ? *(const float4*)(ap + c * 4) : make_float4(0, 0, 0, 0);
            av[c * 4 + 0] = t.x; av[c * 4 + 1] = t.y;
            av[c * 4 + 2] = t.z; av[c * 4 + 3] = t.w;
        }
#pragma unroll
        for (int c = 0; c < 16; ++c)
            wv[c] = W[(size_t)(k0 + kh + c) * N + n0 + sm];
        __syncthreads();
#pragma unroll
        for (int c = 0; c < 16; ++c) {
            SPLIT_STORE(Ah, Al, sm, kh, c, av[c]);
            SPLIT_STORE(Bh, Bl, sm, kh, c, wv[c]);
        }
        __syncthreads();
        bf16x8 afh[4], afl[4], bfh[4], bfl[4];
#pragma unroll
        for (int i = 0; i < 4; ++i) {
            afh[i] = *(const bf16x8*)(&Ah[wm + i * 16 + lr][q * 8]);
            afl[i] = *(const bf16x8*)(&Al[wm + i * 16 + lr][q * 8]);
        }
#pragma unroll
        for (int j = 0; j < 4; ++j) {
            bfh[j] = *(const bf16x8*)(&Bh[wn + j * 16 + lr][q * 8]);
            bfl[j] = *(const bf16x8*)(&Bl[wn + j * 16 + lr][q * 8]);
        }
#pragma unroll
        for (int i = 0; i < 4; ++i)
#pragma unroll
            for (int j = 0; j < 4; ++j) {
                MFMA3(acc[i][j], afh[i], afl[i], bfh[j], bfl[j]);
            }
    }
#pragma unroll
    for (int i = 0; i < 4; ++i)
#pragma unroll
        for (int r = 0; r < 4; ++r) {
            int m = m0 + wm + i * 16 + q * 4 + r;
            if (m < M) {
#pragma unroll
                for (int j = 0; j < 4; ++j) {
                    int n = n0 + wn + j * 16 + lr;
                    C[(size_t)m * N + n] = acc[i][j][r] + bias[n];
                }
            }
        }
}

// ---- generic 512x512 projection (o-proj) -----------------------------------
__global__ __launch_bounds__(256) void mgemm_bias(const float* __restrict__ A,
                                                  const float* __restrict__ W,
                                                  const float* __restrict__ bias,
                                                  float* __restrict__ C, int M) {
    __shared__ __align__(16) __bf16 Ah[128][40], Al[128][40];
    __shared__ __align__(16) __bf16 Bh[128][40], Bl[128][40];
    const int K = 512, N = 512;
    int tid = threadIdx.x;
    int n0 = blockIdx.x * 128;
    int m0 = blockIdx.y * 128;
    int w = tid >> 6, lane = tid & 63;
    int wm = (w >> 1) * 64, wn = (w & 1) * 64;
    int q = lane >> 4, lr = lane & 15;
    int sm = tid & 127, kh = (tid >> 7) * 16;
    bool mval = (m0 + sm) < M;
    f32x4 acc[4][4];
#pragma unroll
    for (int i = 0; i < 4; ++i)
#pragma unroll
        for (int j = 0; j < 4; ++j)
#pragma unroll
            for (int r = 0; r < 4; ++r) acc[i][j][r] = 0.0f;
    for (int k0 = 0; k0 < K; k0 += 32) {
        float av[16], wv[16];
        const float* ap = A + (size_t)(m0 + sm) * K + k0 + kh;
#pragma unroll
        for (int c = 0; c < 4; ++c) {
            float4 t = mval ? *(const float4*)(ap + c * 4) : make_float4(0, 0, 0, 0);
            av[c * 4 + 0] = t.x; av[c * 4 + 1] = t.y;
            av[c * 4 + 2] = t.z; av[c * 4 + 3] = t.w;
        }
#pragma unroll
        for (int c = 0; c < 16; ++c)
            wv[c] = W[(size_t)(k0 + kh + c) * N + n0 + sm];
        __syncthreads();
#pragma unroll
        for (int c = 0; c < 16; ++c) {
            SPLIT_STORE(Ah, Al, sm, kh, c, av[c]);
            SPLIT_STORE(Bh, Bl, sm, kh, c, wv[c]);
        }
        __syncthreads();
        bf16x8 afh[4], afl[4], bfh[4], bfl[4];
#pragma unroll
        for (int i = 0; i < 4; ++i) {
            afh[i] = *(const bf16x8*)(&Ah[wm + i * 16 + lr][q * 8]);
            afl[i] = *(const bf16x8*)(&Al[wm + i * 16 + lr][q * 8]);
        }
#pragma unroll
        for (int j = 0; j < 4; ++j) {
            bfh[j] = *(const bf16x8*)(&Bh[wn + j * 16 + lr][q * 8]);
            bfl[j] = *(const bf16x8*)(&Bl[wn + j * 16 + lr][q * 8]);
        }
#pragma unroll
        for (int i = 0; i < 4; ++i)
#pragma unroll
            for (int j = 0; j < 4; ++j) {
                MFMA3(acc[i][j], afh[i], afl[i], bfh[j], bfl[j]);
            }
    }
#pragma unroll
    for (int i = 0; i < 4; ++i)
#pragma unroll
        for (int r = 0; r < 4; ++r) {
            int m = m0 + wm + i * 16 + q * 4 + r;
            if (m < M) {
#pragma unroll
                for (int j = 0; j < 4; ++j) {
                    int n = n0 + wn + j * 16 + lr;
                    C[(size_t)m * N + n] = acc[i][j][r] + bias[n];
                }
            }
        }
}

// ---- GEGLU: h[m][n] = (A@Wa+ba)*gelu(A@Wg+bg), h f32 [M x 2048] ------------
__global__ __launch_bounds__(256) void mgemm_geglu(const float* __restrict__ A,
                                                   const float* __restrict__ W,
                                                   const float* __restrict__ bias,
                                                   float* __restrict__ H, int M) {
    __shared__ __align__(16) __bf16 Ah[128][40], Al[128][40];
    __shared__ __align__(16) __bf16 Bah[128][40], Bal[128][40];
    __shared__ __align__(16) __bf16 Bgh[128][40], Bgl[128][40];
    const int K = 512, NW = 4096;
    int tid = threadIdx.x;
    int n0 = blockIdx.x * 128;
    int m0 = blockIdx.y * 128;
    int w = tid >> 6, lane = tid & 63;
    int wm = (w >> 1) * 64, wn = (w & 1) * 64;
    int q = lane >> 4, lr = lane & 15;
    int sm = tid & 127, kh = (tid >> 7) * 16;
    bool mval = (m0 + sm) < M;
    f32x4 acca[4][4], accg[4][4];
#pragma unroll
    for (int i = 0; i < 4; ++i)
#pragma unroll
        for (int j = 0; j < 4; ++j)
#pragma unroll
            for (int r = 0; r < 4; ++r) { acca[i][j][r] = 0.0f; accg[i][j][r] = 0.0f; }
    for (int k0 = 0; k0 < K; k0 += 32) {
        float av[16], wa[16], wg[16];
        const float* ap = A + (size_t)(m0 + sm) * K + k0 + kh;
#pragma unroll
        for (int c = 0; c < 4; ++c) {
            float4 t = mval ? *(const float4*)(ap + c * 4) : make_float4(0, 0, 0, 0);
            av[c * 4 + 0] = t.x; av[c * 4 + 1] = t.y;
            av[c * 4 + 2] = t.z; av[c * 4 + 3] = t.w;
        }
#pragma unroll
        for (int c = 0; c < 16; ++c) {
            size_t ro = (size_t)(k0 + kh + c) * NW + n0 + sm;
            wa[c] = W[ro];
            wg[c] = W[ro + 2048];
        }
        __syncthreads();
#pragma unroll
        for (int c = 0; c < 16; ++c) {
            SPLIT_STORE(Ah, Al, sm, kh, c, av[c]);
            SPLIT_STORE(Bah, Bal, sm, kh, c, wa[c]);
            SPLIT_STORE(Bgh, Bgl, sm, kh, c, wg[c]);
        }
        __syncthreads();
        bf16x8 afh[4], afl[4];
#pragma unroll
        for (int i = 0; i < 4; ++i) {
            afh[i] = *(const bf16x8*)(&Ah[wm + i * 16 + lr][q * 8]);
            afl[i] = *(const bf16x8*)(&Al[wm + i * 16 + lr][q * 8]);
        }
#pragma unroll
        for (int j = 0; j < 4; ++j) {
            bf16x8 bah = *(const bf16x8*)(&Bah[wn + j * 16 + lr][q * 8]);
            bf16x8 bal = *(const bf16x8*)(&Bal[wn + j * 16 + lr][q * 8]);
            bf16x8 bgh = *(const bf16x8*)(&Bgh[wn + j * 16 + lr][q * 8]);
            bf16x8 bgl = *(const bf16x8*)(&Bgl[wn + j * 16 + lr][q * 8]);
#pragma unroll
            for (int i = 0; i < 4; ++i) {
                MFMA3(acca[i][j], afh[i], afl[i], bah, bal);
                MFMA3(accg[i][j], afh[i], afl[i], bgh, bgl);
            }
        }
    }
#pragma unroll
    for (int i = 0; i < 4; ++i)
#pragma unroll
        for (int r = 0; r < 4; ++r) {
            int m = m0 + wm + i * 16 + q * 4 + r;
            if (m < M) {
#pragma unroll
                for (int j = 0; j < 4; ++j) {
                    int n = n0 + wn + j * 16 + lr;
                    float a = acca[i][j][r] + bias[n];
                    float g = accg[i][j][r] + bias[2048 + n];
                    float gel = 0.5f * g * (1.0f + erff(g * 0.70710678118654752f));
                    H[(size_t)m * HIDDEN + n] = a * gel;
                }
            }
        }
}

// ---- FFN out: C = H(f32, K=2048) @ W + bias --------------------------------
__global__ __launch_bounds__(256) void mgemm_ffout(const float* __restrict__ H,
                                                   const float* __restrict__ W,
                                                   const float* __restrict__ bias,
                                                   float* __restrict__ C, int M) {
    __shared__ __align__(16) __bf16 Ah[128][40], Al[128][40];
    __shared__ __align__(16) __bf16 Bh[128][40], Bl[128][40];
    const int K = 2048, N = 512;
    int tid = threadIdx.x;
    int n0 = blockIdx.x * 128;
    int m0 = blockIdx.y * 128;
    int w = tid >> 6, lane = tid & 63;
    int wm = (w >> 1) * 64, wn = (w & 1) * 64;
    int q = lane >> 4, lr = lane & 15;
    int sm = tid & 127, kh = (tid >> 7) * 16;
    bool mval = (m0 + sm) < M;
    f32x4 acc[4][4];
#pragma unroll
    for (int i = 0; i < 4; ++i)
#pragma unroll
        for (int j = 0; j < 4; ++j)
#pragma unroll
            for (int r = 0; r < 4; ++r) acc[i][j][r] = 0.0f;
    for (int k0 = 0; k0 < K; k0 += 32) {
        float av[16], wv[16];
        const float* ap = H + (size_t)(m0 + sm) * K + k0 + kh;
#pragma unroll
        for (int c = 0; c < 4; ++c) {
            float4 t = mval ? *(const float4*)(ap + c * 4) : make_float4(0, 0, 0, 0);
            av[c * 4 + 0] = t.x; av[c * 4 + 1] = t.y;
            av[c * 4 + 2] = t.z; av[c * 4 + 3] = t.w;
        }
#pragma unroll
        for (int c = 0; c < 16; ++c)
            wv[c] = W[(size_t)(k0 + kh + c) * N + n0 + sm];
        __syncthreads();
#pragma unroll
        for (int c = 0; c < 16; ++c) {
            SPLIT_STORE(Ah, Al, sm, kh, c, av[c]);
            SPLIT_STORE(Bh, Bl, sm, kh, c, wv[c]);
        }
        __syncthreads();
        bf16x8 afh[4], afl[4], bfh[4], bfl[4];
#pragma unroll
        for (int i = 0; i < 4; ++i) {
            afh[i] = *(const bf16x8*)(&Ah[wm + i * 16 + lr][q * 8]);
            afl[i] = *(const bf16x8*)(&Al[wm + i * 16 + lr][q * 8]);
        }
#pragma unroll
        for (int j = 0; j < 4; ++j) {
            bfh[j] = *(const bf16x8*)(&Bh[wn + j * 16 + lr][q * 8]);
            bfl[j] = *(const bf16x8*)(&Bl[wn + j * 16 + lr][q * 8]);
        }
#pragma unroll
        for (int i = 0; i < 4; ++i)
#pragma unroll
            for (int j = 0; j < 4; ++j) {
                MFMA3(acc[i][j], afh[i], afl[i], bfh[j], bfl[j]);
            }
    }
#pragma unroll
    for (int i = 0; i < 4; ++i)
#pragma unroll
        for (int r = 0; r < 4; ++r) {
            int m = m0 + wm + i * 16 + q * 4 + r;
            if (m < M) {
#pragma unroll
                for (int j = 0; j < 4; ++j) {
                    int n = n0 + wn + j * 16 + lr;
                    C[(size_t)m * N + n] = acc[i][j][r] + bias[n];
                }
            }
        }
}

// ---- flash attention (unchanged) -------------------------------------------
__global__ __launch_bounds__(256) void fattn_kernel(const float* __restrict__ Q,
                                                    const float* __restrict__ K,
                                                    const float* __restrict__ V,
                                                    float* __restrict__ O) {
    __shared__ __align__(16) float Qs[64][68];
    __shared__ __align__(16) float KPs[64][68];
    __shared__ __align__(16) float Vs[64][68];
    int tid = threadIdx.x;
    int tx = tid & 15, ty = tid >> 4;
    int h = blockIdx.z;
    int hoff = h * DH;
    int qbase, base0, len0, base1, len1;
    if (blockIdx.y < 6) {
        int f = blockIdx.y;
        qbase = f * SEQ;
        base0 = f * SEQ; len0 = SEQ;
        int jl = f - 4; if (jl < 0) jl = 0;
        base1 = LZ + jl * SEQ; len1 = (f - jl) * SEQ;
    } else {
        int f = blockIdx.y - 6;
        qbase = LZ + f * SEQ;
        base0 = LZ; len0 = (f + 1) * SEQ;
        base1 = 0; len1 = 0;
    }
    int q0 = blockIdx.x * 64;
    int qvalid = SEQ - q0; if (qvalid > 64) qvalid = 64;
    {
        int am = tid >> 2, ad = (tid & 3) * 4;
        const float* qp = Q + (size_t)(qbase + q0 + am) * DM + hoff;
        bool v = am < qvalid;
#pragma unroll
        for (int c = 0; c < 4; ++c) {
            float4 q4 = v ? *(const float4*)(qp + ad + c * 16) : make_float4(0, 0, 0, 0);
            Qs[ad + c * 16 + 0][am] = q4.x;
            Qs[ad + c * 16 + 1][am] = q4.y;
            Qs[ad + c * 16 + 2][am] = q4.z;
            Qs[ad + c * 16 + 3][am] = q4.w;
        }
    }
    float o_acc[4][4] = {{0.0f}};
    float m_i[4] = {-1e30f, -1e30f, -1e30f, -1e30f};
    float l_i[4] = {0.0f, 0.0f, 0.0f, 0.0f};
    for (int rng = 0; rng < 2; ++rng) {
        int base = rng ? base1 : base0;
        int len = rng ? len1 : len0;
        for (int t0 = 0; t0 < len; t0 += 64) {
            int valid = len - t0; if (valid > 64) valid = 64;
            __syncthreads();
            {
                int an = tid >> 2, ad = (tid & 3) * 4;
                const float* kp = K + (size_t)(base + t0 + an) * DM + hoff;
                bool v = an < valid;
#pragma unroll
                for (int c = 0; c < 4; ++c) {
                    float4 k4 = v ? *(const float4*)(kp + ad + c * 16) : make_float4(0, 0, 0, 0);
                    KPs[ad + c * 16 + 0][an] = k4.x;
                    KPs[ad + c * 16 + 1][an] = k4.y;
                    KPs[ad + c * 16 + 2][an] = k4.z;
                    KPs[ad + c * 16 + 3][an] = k4.w;
                }
#pragma unroll
                for (int c = 0; c < 4; ++c) {
                    int flat = c * 256 + tid;
                    int n = flat >> 4, dg = (flat & 15) * 4;
                    float4 v4 = (n < valid)
                        ? *(const float4*)(V + (size_t)(base + t0 + n) * DM + hoff + dg)
                        : make_float4(0, 0, 0, 0);
                    *(float4*)(&Vs[n][dg]) = v4;
                }
            }
            __syncthreads();
            float p[4][4] = {{0.0f}};
            for (int d = 0; d < 64; ++d) {
                float4 a4 = *(const float4*)(&Qs[d][ty * 4]);
                float4 b4 = *(const float4*)(&KPs[d][tx * 4]);
                const float aa[4] = {a4.x, a4.y, a4.z, a4.w};
                const float bb[4] = {b4.x, b4.y, b4.z, b4.w};
#pragma unroll
                for (int i = 0; i < 4; ++i)
#pragma unroll
                    for (int j = 0; j < 4; ++j) p[i][j] += aa[i] * bb[j];
            }
            float alpha[4];
#pragma unroll
            for (int i = 0; i < 4; ++i) {
#pragma unroll
                for (int j = 0; j < 4; ++j)
                    p[i][j] = (tx * 4 + j < valid) ? p[i][j] * 0.125f : -1e30f;
                float rmax = fmaxf(fmaxf(p[i][0], p[i][1]), fmaxf(p[i][2], p[i][3]));
#pragma unroll
                for (int msk = 1; msk < 16; msk <<= 1)
                    rmax = fmaxf(rmax, __shfl_xor(rmax, msk));
                float mnew = fmaxf(m_i[i], rmax);
                alpha[i] = __expf(m_i[i] - mnew);
                float rsum = 0.0f;
#pragma unroll
                for (int j = 0; j < 4; ++j) {
                    p[i][j] = __expf(p[i][j] - mnew);
                    rsum += p[i][j];
                }
#pragma unroll
                for (int msk = 1; msk < 16; msk <<= 1)
                    rsum += __shfl_xor(rsum, msk);
                l_i[i] = l_i[i] * alpha[i] + rsum;
                m_i[i] = mnew;
#pragma unroll
                for (int j = 0; j < 4; ++j) o_acc[i][j] *= alpha[i];
            }
            __syncthreads();
#pragma unroll
            for (int i = 0; i < 4; ++i)
#pragma unroll
                for (int j = 0; j < 4; ++j)
                    KPs[tx * 4 + j][ty * 4 + i] = p[i][j];
            __syncthreads();
            for (int n = 0; n < 64; ++n) {
                float4 p4 = *(const float4*)(&KPs[n][ty * 4]);
                float4 v4 = *(const float4*)(&Vs[n][tx * 4]);
                const float pp[4] = {p4.x, p4.y, p4.z, p4.w};
                const float vv[4] = {v4.x, v4.y, v4.z, v4.w};
#pragma unroll
                for (int i = 0; i < 4; ++i)
#pragma unroll
                    for (int j = 0; j < 4; ++j) o_acc[i][j] += pp[i] * vv[j];
            }
        }
    }
#pragma unroll
    for (int i = 0; i < 4; ++i) {
        int row = ty * 4 + i;
        if (row < qvalid) {
            float inv = 1.0f / l_i[i];
            float4 o4 = make_float4(o_acc[i][0] * inv, o_acc[i][1] * inv,
                                    o_acc[i][2] * inv, o_acc[i][3] * inv);
            *(float4*)(O + (size_t)(qbase + q0 + row) * DM + hoff + tx * 4) = o4;
        }
    }
}

// ---------------- gate1 + residual add ----------------
__global__ void gate1add_kernel(const float* __restrict__ xn,
                                const float* __restrict__ proj,
                                float* __restrict__ y2,
                                const float* __restrict__ params) {
    int idx = blockIdx.x * blockDim.x + threadIdx.x;
    if (idx >= LT * DM) return;
    int T = idx >> 9, d = idx & 511;
    int r = (T < LZ) ? (T / SEQ) : 6;
    y2[idx] = xn[idx] * params[r * 3072 + 2048 + d] + proj[idx];
}

// ---------------- gate2 ----------------
__global__ void gate2_kernel(const float* __restrict__ src, float* __restrict__ state,
                             const float* __restrict__ params) {
    int idx = blockIdx.x * blockDim.x + threadIdx.x;
    if (idx >= LT * DM) return;
    int T = idx >> 9, d = idx & 511;
    int r = (T < LZ) ? (T / SEQ) : 6;
    state[idx] = src[idx] * params[r * 3072 + 2560 + d];
}

// ---------------- unpatch to FP32 output ------------------
__global__ void unpatch_kernel(const float* __restrict__ state,
                               const float* __restrict__ Wu,
                               const float* __restrict__ bu,
                               float* __restrict__ out) {
    int idx = blockIdx.x * blockDim.x + threadIdx.x;
    if (idx >= DURZ * 3 * 32 * 32) return;
    int w = idx & 31, hh = (idx >> 5) & 31, c = (idx >> 10) % 3, f = idx / (3 * 1024);
    int t = (hh >> 1) * 16 + (w >> 1);
    int j = c * 4 + (hh & 1) * 2 + (w & 1);
    const float* xr = state + (size_t)(f * SEQ + t) * DM;
    float acc = bu[j];
    for (int k = 0; k < DM; ++k) acc += xr[k] * Wu[k * 12 + j];
    out[idx] = acc;
}

extern "C" void kernel_launch(void* const* d_in, const int* in_sizes, int n_in,
                              void* d_out, int out_size, void* d_ws, size_t ws_size,
                              hipStream_t stream) {
    static const int expected_sizes[32] = {
        18432, 15360, 6, 6,
        6144, 512, 6144, 12,
        512, 131072, 1536, 512000,
        3145728, 6144, 3145728, 6144,
        1572864, 3072, 1572864, 3072,
        1572864, 3072, 1572864, 3072,
        1572864, 3072, 1572864, 3072,
        12582912, 24576, 6291456, 3072
    };
    if (n_in != 32) {
        fill_kernel<<<(18432 + 255) / 256, 256, 0, stream>>>((float*)d_out, 18432, 3.0f);
        return;
    }
    for (int i = 0; i < 32; ++i) {
        if (in_sizes[i] != expected_sizes[i]) {
            fill_kernel<<<(18432 + 255) / 256, 256, 0, stream>>>((float*)d_out, 18432,
                                                                 4.0f + (float)i);
            return;
        }
    }

    const float* z = (const float*)d_in[0];
    const float* frames = (const float*)d_in[1];
    const int* actions = (const int*)d_in[2];
    const int* ts = (const int*)d_in[3];
    const float* W_patch = (const float*)d_in[4];
    const float* b_patch = (const float*)d_in[5];
    const float* W_unpatch = (const float*)d_in[6];
    const float* b_unpatch = (const float*)d_in[7];
    const float* registers = (const float*)d_in[8];
    const float* pe_grid = (const float*)d_in[9];
    const float* action_emb = (const float*)d_in[10];
    const float* time_emb = (const float*)d_in[11];
    const float* W_mod1 = (const float*)d_in[12];
    const float* b_mod1 = (const float*)d_in[13];
    const float* W_mod2 = (const float*)d_in[14];
    const float* b_mod2 = (const float*)d_in[15];
    const float* W_q = (const float*)d_in[16];
    const float* b_q = (const float*)d_in[17];
    const float* W_k = (const float*)d_in[18];
    const float* b_k = (const float*)d_in[19];
    const float* W_v = (const float*)d_in[20];
    const float* b_v = (const float*)d_in[21];
    const float* W_o = (const float*)d_in[22];
    const float* b_o = (const float*)d_in[23];
    const float* W_g1 = (const float*)d_in[24];
    const float* b_g1 = (const float*)d_in[25];
    const float* W_g2 = (const float*)d_in[26];
    const float* b_g2 = (const float*)d_in[27];
    const float* W_geglu = (const float*)d_in[28];
    const float* b_geglu = (const float*)d_in[29];
    const float* W_ffout = (const float*)d_in[30];
    const float* b_ffout = (const float*)d_in[31];

    const size_t S = (size_t)LT * DM;  // 1,447,424
    size_t need = (8 * S + 129024 + 7168) * sizeof(float);
    if (ws_size < need) {
        fill_kernel<<<(18432 + 255) / 256, 256, 0, stream>>>((float*)d_out, 18432, 40.0f);
        return;
    }
    float* ws = (float*)d_ws;
    float* state = ws;
    float* xn = ws + S;
    float* qb = ws + 2 * S;
    float* kb = ws + 3 * S;
    float* vb = ws + 4 * S;
    float* attno = ws + 5 * S;      // reused as y2 after o-proj
    float* proj = ws + 6 * S;
    float* params = ws + 8 * S;
    float* condraw = params + 129024;
    float* condsilu = condraw + 3584;
    float* hbuf = qb;               // LT x 2048 f32 = 4S region (q/k/v/attno dead)

    embed_kernel<<<LT, 256, 0, stream>>>(z, frames, actions, W_patch, b_patch,
                                         registers, pe_grid, action_emb, state);
    cond_kernel<<<(7 * 512 + 255) / 256, 256, 0, stream>>>(ts, time_emb, condraw, condsilu);
    params_kernel<<<(6 * 7 * 3072 + 255) / 256, 256, 0, stream>>>(
        condraw, condsilu, W_mod1, b_mod1, W_mod2, b_mod2, W_g1, b_g1, W_g2, b_g2, params);

    const int MT = (LT + 127) / 128;  // 23
    dim3 gqkv(12, MT);
    dim3 g1(4, MT);
    dim3 gglu(16, MT);
    dim3 gattn(5, 11, NHEADS);
    int ew = (LT * DM + 255) / 256;
    for (int i = 0; i < 6; ++i) {
        const float* P = params + i * 21504;
        lnmod_kernel<<<LT, 256, 0, stream>>>(state, xn, P, 0);
        mgemm_qkv<<<gqkv, 256, 0, stream>>>(xn,
            W_q + (size_t)i * DM * DM, W_k + (size_t)i * DM * DM, W_v + (size_t)i * DM * DM,
            b_q + i * DM, b_k + i * DM, b_v + i * DM, qb, kb, vb, LT);
        fattn_kernel<<<gattn, 256, 0, stream>>>(qb, kb, vb, attno);
        mgemm_bias<<<g1, 256, 0, stream>>>(attno, W_o + (size_t)i * DM * DM,
                                           b_o + i * DM, proj, LT);
        gate1add_kernel<<<ew, 256, 0, stream>>>(xn, proj, attno, P);  // attno := y2
        lnmod_kernel<<<LT, 256, 0, stream>>>(attno, xn, P, 1024);
        mgemm_geglu<<<gglu, 256, 0, stream>>>(xn, W_geglu + (size_t)i * DM * 4096,
                                              b_geglu + i * 4096, hbuf, LT);
        mgemm_ffout<<<g1, 256, 0, stream>>>(hbuf, W_ffout + (size_t)i * HIDDEN * DM,
                                            b_ffout + i * DM, proj, LT);
        gate2_kernel<<<ew, 256, 0, stream>>>(proj, state, P);
    }
    unpatch_kernel<<<(DURZ * 3 * 32 * 32 + 255) / 256, 256, 0, stream>>>(
        state, W_unpatch, b_unpatch, (float*)d_out);
}